// Round 1
// baseline (2259.774 us; speedup 1.0000x reference)
//
#include <hip/hip_runtime.h>

// GraphSAGE 2-layer forward, f32.
// N=50000, feat=hid=64, nclass=10, E=1.25M.
// ws layout (floats): [cnt N][agg1 64N][agg2 64N][h1 64N]

static constexpr int FEAT = 64;
static constexpr int NCLASS = 10;

// ---- edge scatter: agg[dst][:] += x[src][:]; 16 threads/edge, float4 each ----
__global__ __launch_bounds__(256) void scatter_kernel(
    const float* __restrict__ x,
    const int* __restrict__ src,
    const int* __restrict__ dst,
    float* __restrict__ agg,
    float* __restrict__ cnt,   // null for layer 2 (degrees already counted)
    int E) {
  int t = blockIdx.x * 256 + threadIdx.x;
  int e = t >> 4;
  if (e >= E) return;
  int p = t & 15;
  int s = src[e];
  int d = dst[e];
  float4 v = ((const float4*)(x + (size_t)s * FEAT))[p];
  float* a = agg + (size_t)d * FEAT + p * 4;
  atomicAdd(a + 0, v.x);
  atomicAdd(a + 1, v.y);
  atomicAdd(a + 2, v.z);
  atomicAdd(a + 3, v.w);
  if (cnt != nullptr && p == 0) atomicAdd(cnt + d, 1.0f);
}

// ---- layer 1 dense: h = relu(l2norm(mean@Wl^T + b + x@Wr^T)); wave/node ----
__global__ __launch_bounds__(256) void dense1_kernel(
    const float* __restrict__ x,
    const float* __restrict__ agg,
    const float* __restrict__ cnt,
    const float* __restrict__ Wl,   // [64,64] row-major: Wl[j][k]
    const float* __restrict__ b,
    const float* __restrict__ Wr,
    float* __restrict__ h,
    int N) {
  __shared__ float Wl_s[64 * 65];   // +1 pad -> bank (j+k)%32, 2-way = free
  __shared__ float Wr_s[64 * 65];
  __shared__ float b_s[64];
  __shared__ float xm_s[4][2][64];  // [wave][x|mean][k]

  int tid = threadIdx.x;
  for (int i = tid; i < 64 * 64; i += 256) {
    int r = i >> 6, c = i & 63;
    Wl_s[r * 65 + c] = Wl[i];
    Wr_s[r * 65 + c] = Wr[i];
  }
  if (tid < 64) b_s[tid] = b[tid];

  int wave = tid >> 6;
  int lane = tid & 63;
  int node = blockIdx.x * 4 + wave;
  bool active = (node < N);

  if (active) {
    float xv = x[(size_t)node * FEAT + lane];
    float av = agg[(size_t)node * FEAT + lane];
    float invc = 1.0f / fmaxf(cnt[node], 1.0f);
    xm_s[wave][0][lane] = xv;
    xm_s[wave][1][lane] = av * invc;
  }
  __syncthreads();
  if (!active) return;

  float acc = b_s[lane];
  const float* wl = Wl_s + lane * 65;
  const float* wr = Wr_s + lane * 65;
#pragma unroll
  for (int k = 0; k < 64; ++k) {
    acc = fmaf(xm_s[wave][1][k], wl[k], acc);
    acc = fmaf(xm_s[wave][0][k], wr[k], acc);
  }

  // L2 norm across 64 lanes
  float ss = acc * acc;
#pragma unroll
  for (int off = 32; off; off >>= 1) ss += __shfl_xor(ss, off);
  float scale = 1.0f / fmaxf(sqrtf(ss), 1e-12f);
  float v = acc * scale;
  h[(size_t)node * FEAT + lane] = fmaxf(v, 0.0f);  // relu
}

// ---- layer 2 dense + log_softmax: thread/node ----
__global__ __launch_bounds__(128) void dense2_kernel(
    const float* __restrict__ h,
    const float* __restrict__ agg,
    const float* __restrict__ cnt,
    const float* __restrict__ Wl,   // [10,64]
    const float* __restrict__ b,
    const float* __restrict__ Wr,
    float* __restrict__ out,
    int N) {
  __shared__ float Wl_s[NCLASS * 64];
  __shared__ float Wr_s[NCLASS * 64];
  __shared__ float b_s[NCLASS];

  int tid = threadIdx.x;
  for (int i = tid; i < NCLASS * 64; i += 128) {
    Wl_s[i] = Wl[i];
    Wr_s[i] = Wr[i];
  }
  if (tid < NCLASS) b_s[tid] = b[tid];
  __syncthreads();

  int node = blockIdx.x * 128 + tid;
  if (node >= N) return;

  float invc = 1.0f / fmaxf(cnt[node], 1.0f);
  float acc[NCLASS];
#pragma unroll
  for (int c = 0; c < NCLASS; ++c) acc[c] = b_s[c];

  const float4* h4 = (const float4*)(h + (size_t)node * FEAT);
  const float4* a4 = (const float4*)(agg + (size_t)node * FEAT);
#pragma unroll
  for (int k4 = 0; k4 < 16; ++k4) {
    float4 hv = h4[k4];
    float4 av = a4[k4];
    float m0 = av.x * invc, m1 = av.y * invc, m2 = av.z * invc, m3 = av.w * invc;
    int k = k4 * 4;
#pragma unroll
    for (int c = 0; c < NCLASS; ++c) {
      float a = acc[c];
      a = fmaf(m0, Wl_s[c * 64 + k + 0], fmaf(hv.x, Wr_s[c * 64 + k + 0], a));
      a = fmaf(m1, Wl_s[c * 64 + k + 1], fmaf(hv.y, Wr_s[c * 64 + k + 1], a));
      a = fmaf(m2, Wl_s[c * 64 + k + 2], fmaf(hv.z, Wr_s[c * 64 + k + 2], a));
      a = fmaf(m3, Wl_s[c * 64 + k + 3], fmaf(hv.w, Wr_s[c * 64 + k + 3], a));
      acc[c] = a;
    }
  }

  // L2 normalize over the 10 outputs
  float ss = 0.0f;
#pragma unroll
  for (int c = 0; c < NCLASS; ++c) ss += acc[c] * acc[c];
  float scale = 1.0f / fmaxf(sqrtf(ss), 1e-12f);

  // log_softmax
  float m = -1e30f;
  float v[NCLASS];
#pragma unroll
  for (int c = 0; c < NCLASS; ++c) {
    v[c] = acc[c] * scale;
    m = fmaxf(m, v[c]);
  }
  float lse = 0.0f;
#pragma unroll
  for (int c = 0; c < NCLASS; ++c) lse += __expf(v[c] - m);
  lse = m + __logf(lse);

  float* o = out + (size_t)node * NCLASS;
#pragma unroll
  for (int c = 0; c < NCLASS; ++c) o[c] = v[c] - lse;
}

extern "C" void kernel_launch(void* const* d_in, const int* in_sizes, int n_in,
                              void* d_out, int out_size, void* d_ws, size_t ws_size,
                              hipStream_t stream) {
  const float* features = (const float*)d_in[0];
  const int* edge_index = (const int*)d_in[1];
  const float* W1_l = (const float*)d_in[2];
  const float* b1   = (const float*)d_in[3];
  const float* W1_r = (const float*)d_in[4];
  const float* W2_l = (const float*)d_in[5];
  const float* b2   = (const float*)d_in[6];
  const float* W2_r = (const float*)d_in[7];
  float* out = (float*)d_out;

  const int N = in_sizes[0] / FEAT;    // 50000
  const int E = in_sizes[1] / 2;       // 1250000
  const int* src = edge_index;
  const int* dst = edge_index + E;

  float* ws = (float*)d_ws;
  float* cnt  = ws;                       // [N]
  float* agg1 = cnt + N;                  // [N*64]
  float* agg2 = agg1 + (size_t)N * FEAT;  // [N*64]
  float* h1   = agg2 + (size_t)N * FEAT;  // [N*64]

  // zero cnt + agg1 + agg2 (contiguous)
  hipMemsetAsync(d_ws, 0, (size_t)(1 + 2 * FEAT) * N * sizeof(float), stream);

  int scatter_blocks = (E * 16 + 255) / 256;

  // layer 1
  scatter_kernel<<<scatter_blocks, 256, 0, stream>>>(features, src, dst, agg1, cnt, E);
  dense1_kernel<<<(N + 3) / 4, 256, 0, stream>>>(features, agg1, cnt, W1_l, b1, W1_r, h1, N);

  // layer 2
  scatter_kernel<<<scatter_blocks, 256, 0, stream>>>(h1, src, dst, agg2, nullptr, E);
  dense2_kernel<<<(N + 127) / 128, 128, 0, stream>>>(h1, agg2, cnt, W2_l, b2, W2_r, out, N);
}

// Round 2
// 515.219 us; speedup vs baseline: 4.3860x; 4.3860x over previous
//
#include <hip/hip_runtime.h>

// GraphSAGE 2-layer forward, f32, CSR gather-aggregation (no feature atomics).
// N=50000, feat=hid=64, nclass=10, E=1.25M.
// ws layout (bytes, 16-aligned):
//   deg     [N]    int    @ 0
//   row_ptr [N+1]  int    @ 200000
//   cursor  [N]    int    @ 400016
//   col     [E]    int    @ 600016   (src ids sorted by dst)
//   h1      [N*64] float  @ 5600016

static constexpr int FEAT = 64;
static constexpr int NCLASS = 10;

// ---- CSR step 1: in-degree histogram ----
__global__ __launch_bounds__(256) void hist_kernel(
    const int* __restrict__ dst, int* __restrict__ deg, int E) {
  int e = blockIdx.x * 256 + threadIdx.x;
  if (e < E) atomicAdd(&deg[dst[e]], 1);
}

// ---- CSR step 2: exclusive scan of deg -> row_ptr, cursor (single block) ----
__global__ __launch_bounds__(1024) void scan_kernel(
    const int* __restrict__ deg, int* __restrict__ row_ptr,
    int* __restrict__ cursor, int N) {
  __shared__ int sums[1024];
  int t = threadIdx.x;
  int C = (N + 1023) / 1024;  // chunk per thread
  int beg = t * C;
  int end = min(beg + C, N);
  int s = 0;
  for (int i = beg; i < end; ++i) s += deg[i];
  sums[t] = s;
  __syncthreads();
  // Hillis-Steele inclusive scan over thread totals
  for (int off = 1; off < 1024; off <<= 1) {
    int v = (t >= off) ? sums[t - off] : 0;
    __syncthreads();
    sums[t] += v;
    __syncthreads();
  }
  int run = (t == 0) ? 0 : sums[t - 1];  // exclusive prefix of this chunk
  for (int i = beg; i < end; ++i) {
    row_ptr[i] = run;
    cursor[i] = run;
    run += deg[i];
  }
  if (t == 1023) row_ptr[N] = sums[1023];
}

// ---- CSR step 3: bucket fill (counting sort of src by dst) ----
__global__ __launch_bounds__(256) void fill_kernel(
    const int* __restrict__ src, const int* __restrict__ dst,
    int* __restrict__ cursor, int* __restrict__ col, int E) {
  int e = blockIdx.x * 256 + threadIdx.x;
  if (e >= E) return;
  int pos = atomicAdd(&cursor[dst[e]], 1);
  col[pos] = src[e];
}

// ---- layer 1: gather-aggregate + dense + l2norm + relu; wave per node ----
__global__ __launch_bounds__(256) void agg_dense1_kernel(
    const float* __restrict__ x,
    const int* __restrict__ row_ptr,
    const int* __restrict__ col,
    const float* __restrict__ Wl,   // [64,64] row-major Wl[j][k]
    const float* __restrict__ b,
    const float* __restrict__ Wr,
    float* __restrict__ h,
    int N) {
  __shared__ float Wl_s[64 * 65];   // +1 pad: lane j reads row j -> 2-way, free
  __shared__ float Wr_s[64 * 65];
  __shared__ float b_s[64];
  __shared__ float xm_s[4][2][64];  // per-wave: [x | mean][k]

  int tid = threadIdx.x;
  for (int i = tid; i < 64 * 64; i += 256) {
    int r = i >> 6, c = i & 63;
    Wl_s[r * 65 + c] = Wl[i];
    Wr_s[r * 65 + c] = Wr[i];
  }
  if (tid < 64) b_s[tid] = b[tid];
  __syncthreads();

  int wave = tid >> 6;
  int lane = tid & 63;
  int node = blockIdx.x * 4 + wave;
  if (node >= N) return;

  int beg = row_ptr[node];
  int end = row_ptr[node + 1];
  float acc = 0.0f;
  int e = beg;
  for (; e + 3 < end; e += 4) {   // unroll-4: 4 row loads in flight
    int s0 = col[e + 0], s1 = col[e + 1], s2 = col[e + 2], s3 = col[e + 3];
    float v0 = x[(size_t)s0 * FEAT + lane];
    float v1 = x[(size_t)s1 * FEAT + lane];
    float v2 = x[(size_t)s2 * FEAT + lane];
    float v3 = x[(size_t)s3 * FEAT + lane];
    acc += v0 + v1 + v2 + v3;
  }
  for (; e < end; ++e) acc += x[(size_t)col[e] * FEAT + lane];

  float invc = 1.0f / (float)max(end - beg, 1);
  // wave-local LDS round-trip (same wave writes & reads its own slice:
  // lockstep + compiler lgkmcnt makes this safe without a barrier)
  xm_s[wave][0][lane] = x[(size_t)node * FEAT + lane];
  xm_s[wave][1][lane] = acc * invc;

  float o = b_s[lane];
  const float* wl = Wl_s + lane * 65;
  const float* wr = Wr_s + lane * 65;
#pragma unroll
  for (int k = 0; k < 64; ++k) {
    o = fmaf(xm_s[wave][1][k], wl[k], o);
    o = fmaf(xm_s[wave][0][k], wr[k], o);
  }

  float ss = o * o;
#pragma unroll
  for (int off = 32; off; off >>= 1) ss += __shfl_xor(ss, off);
  float scale = 1.0f / fmaxf(sqrtf(ss), 1e-12f);
  h[(size_t)node * FEAT + lane] = fmaxf(o * scale, 0.0f);  // relu
}

// ---- layer 2: gather-aggregate + dense(10) + l2norm + log_softmax; wave/node ----
__global__ __launch_bounds__(256) void agg_dense2_kernel(
    const float* __restrict__ h,
    const int* __restrict__ row_ptr,
    const int* __restrict__ col,
    const float* __restrict__ Wl,   // [10,64]
    const float* __restrict__ b,
    const float* __restrict__ Wr,
    float* __restrict__ out,
    int N) {
  __shared__ float Wl_s[NCLASS * 64];
  __shared__ float Wr_s[NCLASS * 64];
  __shared__ float b_s[NCLASS];

  int tid = threadIdx.x;
  for (int i = tid; i < NCLASS * 64; i += 256) {
    Wl_s[i] = Wl[i];
    Wr_s[i] = Wr[i];
  }
  if (tid < NCLASS) b_s[tid] = b[tid];
  __syncthreads();

  int wave = tid >> 6;
  int lane = tid & 63;
  int node = blockIdx.x * 4 + wave;
  if (node >= N) return;

  int beg = row_ptr[node];
  int end = row_ptr[node + 1];
  float acc = 0.0f;
  int e = beg;
  for (; e + 3 < end; e += 4) {
    int s0 = col[e + 0], s1 = col[e + 1], s2 = col[e + 2], s3 = col[e + 3];
    float v0 = h[(size_t)s0 * FEAT + lane];
    float v1 = h[(size_t)s1 * FEAT + lane];
    float v2 = h[(size_t)s2 * FEAT + lane];
    float v3 = h[(size_t)s3 * FEAT + lane];
    acc += v0 + v1 + v2 + v3;
  }
  for (; e < end; ++e) acc += h[(size_t)col[e] * FEAT + lane];

  float invc = 1.0f / (float)max(end - beg, 1);
  float mean = acc * invc;
  float hv = h[(size_t)node * FEAT + lane];

  // per-lane partials for each class, then butterfly reduce across the wave
  float t[NCLASS];
#pragma unroll
  for (int c = 0; c < NCLASS; ++c)
    t[c] = fmaf(mean, Wl_s[c * 64 + lane], hv * Wr_s[c * 64 + lane]);
#pragma unroll
  for (int off = 32; off; off >>= 1) {
#pragma unroll
    for (int c = 0; c < NCLASS; ++c) t[c] += __shfl_xor(t[c], off);
  }

  // every lane now has all 10 sums; compute normalize + log_softmax redundantly
  float v[NCLASS];
  float ss = 0.0f;
#pragma unroll
  for (int c = 0; c < NCLASS; ++c) {
    v[c] = t[c] + b_s[c];
    ss += v[c] * v[c];
  }
  float scale = 1.0f / fmaxf(sqrtf(ss), 1e-12f);
  float m = -1e30f;
#pragma unroll
  for (int c = 0; c < NCLASS; ++c) {
    v[c] *= scale;
    m = fmaxf(m, v[c]);
  }
  float lse = 0.0f;
#pragma unroll
  for (int c = 0; c < NCLASS; ++c) lse += __expf(v[c] - m);
  lse = m + __logf(lse);

  if (lane == 0) {
    float* o = out + (size_t)node * NCLASS;
#pragma unroll
    for (int c = 0; c < NCLASS; ++c) o[c] = v[c] - lse;
  }
}

extern "C" void kernel_launch(void* const* d_in, const int* in_sizes, int n_in,
                              void* d_out, int out_size, void* d_ws, size_t ws_size,
                              hipStream_t stream) {
  const float* features = (const float*)d_in[0];
  const int* edge_index = (const int*)d_in[1];
  const float* W1_l = (const float*)d_in[2];
  const float* b1   = (const float*)d_in[3];
  const float* W1_r = (const float*)d_in[4];
  const float* W2_l = (const float*)d_in[5];
  const float* b2   = (const float*)d_in[6];
  const float* W2_r = (const float*)d_in[7];
  float* out = (float*)d_out;

  const int N = in_sizes[0] / FEAT;    // 50000
  const int E = in_sizes[1] / 2;       // 1250000
  const int* src = edge_index;
  const int* dst = edge_index + E;

  char* ws = (char*)d_ws;
  int* deg     = (int*)(ws + 0);
  int* row_ptr = (int*)(ws + 200000);
  int* cursor  = (int*)(ws + 400016);
  int* col     = (int*)(ws + 600016);
  float* h1    = (float*)(ws + 5600016);

  hipMemsetAsync(deg, 0, (size_t)N * sizeof(int), stream);

  int eb = (E + 255) / 256;
  hist_kernel<<<eb, 256, 0, stream>>>(dst, deg, E);
  scan_kernel<<<1, 1024, 0, stream>>>(deg, row_ptr, cursor, N);
  fill_kernel<<<eb, 256, 0, stream>>>(src, dst, cursor, col, E);

  int nb = (N + 3) / 4;
  agg_dense1_kernel<<<nb, 256, 0, stream>>>(features, row_ptr, col, W1_l, b1, W1_r, h1, N);
  agg_dense2_kernel<<<nb, 256, 0, stream>>>(h1, row_ptr, col, W2_l, b2, W2_r, out, N);
}

// Round 3
// 492.707 us; speedup vs baseline: 4.5864x; 1.0457x over previous
//
#include <hip/hip_runtime.h>

// GraphSAGE 2-layer forward, f32. Linearity trick: aggregate AFTER the dense
// transform (mean(x_j)@W^T == mean(x_j@W^T)), so gathers are pure memory ops.
// N=50000, feat=hid=64, nclass=10 (padded to 16), E=1.25M.
//
// ws layout (bytes):
//   deg      [N]     int   @ 0
//   partials [64]    int   @ 200000
//   row_ptr  [N+1]   int   @ 200256
//   cursor   [N]     int   @ 400272
//   col      [E]     int   @ 600272
//   p1       [N*64]  f32   @ 5600272   (x @ W1_l^T)
//   q1h1     [N*64]  f32   @ 18400272  (x @ W1_r^T + b1, overwritten by h1)
//   p2       [N*16]  f32   @ 31200272  (h1 @ W2_l^T, cols 10..15 = 0)
//   q2       [N*16]  f32   @ 34400272  (h1 @ W2_r^T + b2, cols 10..15 = 0)
// total 37.6 MB

static constexpr int FEAT = 64;

__device__ __forceinline__ float4 f4add(float4 a, float4 b) {
  return make_float4(a.x + b.x, a.y + b.y, a.z + b.z, a.w + b.w);
}

// ---------------- CSR build ----------------
__global__ __launch_bounds__(256) void hist_kernel(
    const int* __restrict__ dst, int* __restrict__ deg, int E) {
  int e = blockIdx.x * 256 + threadIdx.x;
  if (e < E) atomicAdd(&deg[dst[e]], 1);
}

__global__ __launch_bounds__(1024) void partial_sum_kernel(
    const int* __restrict__ deg, int* __restrict__ partials, int N) {
  __shared__ int ws[16];
  int i = blockIdx.x * 1024 + threadIdx.x;
  int v = (i < N) ? deg[i] : 0;
#pragma unroll
  for (int off = 32; off; off >>= 1) v += __shfl_xor(v, off);
  int w = threadIdx.x >> 6, lane = threadIdx.x & 63;
  if (lane == 0) ws[w] = v;
  __syncthreads();
  if (threadIdx.x == 0) {
    int s = 0;
#pragma unroll
    for (int k = 0; k < 16; ++k) s += ws[k];
    partials[blockIdx.x] = s;
  }
}

__global__ __launch_bounds__(64) void scan_partials_kernel(
    int* __restrict__ partials, int nb) {
  int t = threadIdx.x;
  int orig = (t < nb) ? partials[t] : 0;
  int v = orig;
#pragma unroll
  for (int off = 1; off < 64; off <<= 1) {
    int u = __shfl_up(v, off);
    if (t >= off) v += u;
  }
  if (t < nb) partials[t] = v - orig;  // exclusive
}

__global__ __launch_bounds__(1024) void scan_tile_kernel(
    const int* __restrict__ deg, const int* __restrict__ partials,
    int* __restrict__ row_ptr, int* __restrict__ cursor, int N, int E) {
  __shared__ int ws[16];
  int tid = threadIdx.x;
  int i = blockIdx.x * 1024 + tid;
  int d = (i < N) ? deg[i] : 0;
  int v = d;
  int lane = tid & 63, w = tid >> 6;
#pragma unroll
  for (int off = 1; off < 64; off <<= 1) {
    int u = __shfl_up(v, off);
    if (lane >= off) v += u;
  }
  if (lane == 63) ws[w] = v;
  __syncthreads();
  if (w == 0) {
    int s = (lane < 16) ? ws[lane] : 0;
#pragma unroll
    for (int off = 1; off < 16; off <<= 1) {
      int u = __shfl_up(s, off);
      if (lane >= off) s += u;
    }
    if (lane < 16) ws[lane] = s;  // inclusive over waves
  }
  __syncthreads();
  int woff = (w == 0) ? 0 : ws[w - 1];
  int ex = partials[blockIdx.x] + woff + v - d;
  if (i < N) { row_ptr[i] = ex; cursor[i] = ex; }
  if (i == 0) row_ptr[N] = E;
}

__global__ __launch_bounds__(256) void fill_kernel(
    const int* __restrict__ src, const int* __restrict__ dst,
    int* __restrict__ cursor, int* __restrict__ col, int E) {
  int e = blockIdx.x * 256 + threadIdx.x;
  if (e >= E) return;
  int pos = atomicAdd(&cursor[dst[e]], 1);
  col[pos] = src[e];
}

// ---------------- layer-1 dense: p1 = x@Wl^T, q1 = x@Wr^T + b ----------------
// grid (ceil(N/256), 8): y>>2 = mat (0:Wl->p, 1:Wr->q), y&3 = out-group of 16.
__global__ __launch_bounds__(256) void dense1_kernel(
    const float* __restrict__ x,
    const float* __restrict__ Wl, const float* __restrict__ Wr,
    const float* __restrict__ b,
    float* __restrict__ p, float* __restrict__ q, int N) {
  __shared__ float4 Ws[16 * 16];  // 16 output rows x 16 k-quads
  int mat = blockIdx.y >> 2;
  int og = blockIdx.y & 3;
  const float4* Wg = (const float4*)(mat ? Wr : Wl);
  int tid = threadIdx.x;
  // stage rows og*16 .. og*16+15 (each 64 floats = 16 float4)
  Ws[tid] = Wg[(og * 16) * 16 + tid];  // 256 float4 = exactly blockDim
  __syncthreads();

  int node = blockIdx.x * 256 + tid;
  if (node >= N) return;

  float acc[16];
#pragma unroll
  for (int o = 0; o < 16; ++o) acc[o] = 0.0f;

  const float4* X4 = (const float4*)x;
#pragma unroll
  for (int kq = 0; kq < 16; ++kq) {
    float4 xv = X4[(size_t)node * 16 + kq];
#pragma unroll
    for (int o = 0; o < 16; ++o) {
      float4 w = Ws[o * 16 + kq];  // uniform address -> LDS broadcast
      acc[o] = fmaf(xv.x, w.x, fmaf(xv.y, w.y, fmaf(xv.z, w.z, fmaf(xv.w, w.w, acc[o]))));
    }
  }

  float4* O4 = (float4*)((mat ? q : p) + (size_t)node * FEAT + og * 16);
  const float4* B4 = (const float4*)(b + og * 16);
#pragma unroll
  for (int oq = 0; oq < 4; ++oq) {
    float4 v = make_float4(acc[oq * 4], acc[oq * 4 + 1], acc[oq * 4 + 2], acc[oq * 4 + 3]);
    if (mat) { float4 bv = B4[oq]; v = f4add(v, bv); }
    O4[oq] = v;
  }
}

// ---------------- layer-1 gather: h = relu(l2norm(mean(p)+q)), in-place to q --
// wave per node; 16 lanes per row (float4/lane), 4 edges per iteration.
__global__ __launch_bounds__(256) void gather1_kernel(
    const int* __restrict__ row_ptr, const int* __restrict__ col,
    const float* __restrict__ p, float* __restrict__ qh, int N) {
  int tid = threadIdx.x;
  int wave = tid >> 6, lane = tid & 63;
  int g = lane >> 4, q = lane & 15;
  int node = blockIdx.x * 4 + wave;
  if (node >= N) return;

  int beg = row_ptr[node];
  int end = row_ptr[node + 1];
  const float4* P4 = (const float4*)p;

  float4 acc = make_float4(0.f, 0.f, 0.f, 0.f);
  int e = beg + g;
  for (; e + 4 < end; e += 8) {  // 8 edges in flight per wave
    int s0 = col[e], s1 = col[e + 4];
    float4 v0 = P4[(size_t)s0 * 16 + q];
    float4 v1 = P4[(size_t)s1 * 16 + q];
    acc = f4add(acc, f4add(v0, v1));
  }
  if (e < end) {
    int s = col[e];
    acc = f4add(acc, P4[(size_t)s * 16 + q]);
  }

  // reduce across the 4 edge-groups (lane bits 4,5)
#pragma unroll
  for (int off = 16; off <= 32; off <<= 1) {
    acc.x += __shfl_xor(acc.x, off);
    acc.y += __shfl_xor(acc.y, off);
    acc.z += __shfl_xor(acc.z, off);
    acc.w += __shfl_xor(acc.w, off);
  }

  float invc = 1.0f / (float)max(end - beg, 1);
  float4 qv = ((const float4*)qh)[(size_t)node * 16 + q];
  float4 v = make_float4(fmaf(acc.x, invc, qv.x), fmaf(acc.y, invc, qv.y),
                         fmaf(acc.z, invc, qv.z), fmaf(acc.w, invc, qv.w));

  float ss = v.x * v.x + v.y * v.y + v.z * v.z + v.w * v.w;
#pragma unroll
  for (int off = 1; off <= 8; off <<= 1) ss += __shfl_xor(ss, off);
  float scale = 1.0f / fmaxf(sqrtf(ss), 1e-12f);

  v.x = fmaxf(v.x * scale, 0.0f);
  v.y = fmaxf(v.y * scale, 0.0f);
  v.z = fmaxf(v.z * scale, 0.0f);
  v.w = fmaxf(v.w * scale, 0.0f);
  if (g == 0) ((float4*)qh)[(size_t)node * 16 + q] = v;  // in-place h
}

// ---------------- layer-2 dense: p2 = h@W2l^T, q2 = h@W2r^T + b2 (pad to 16) --
__global__ __launch_bounds__(256) void dense2_kernel(
    const float* __restrict__ h,
    const float* __restrict__ Wl, const float* __restrict__ Wr,
    const float* __restrict__ b,
    float* __restrict__ p2, float* __restrict__ q2, int N) {
  __shared__ float4 Wls[10 * 16];
  __shared__ float4 Wrs[10 * 16];
  __shared__ float bs[10];
  int tid = threadIdx.x;
  if (tid < 160) {
    Wls[tid] = ((const float4*)Wl)[tid];
    Wrs[tid] = ((const float4*)Wr)[tid];
  }
  if (tid < 10) bs[tid] = b[tid];
  __syncthreads();

  int node = blockIdx.x * 256 + tid;
  if (node >= N) return;

  float pa[10], qa[10];
#pragma unroll
  for (int c = 0; c < 10; ++c) { pa[c] = 0.0f; qa[c] = 0.0f; }

  const float4* H4 = (const float4*)h;
#pragma unroll
  for (int kq = 0; kq < 16; ++kq) {
    float4 hv = H4[(size_t)node * 16 + kq];
#pragma unroll
    for (int c = 0; c < 10; ++c) {
      float4 wl = Wls[c * 16 + kq];
      float4 wr = Wrs[c * 16 + kq];
      pa[c] = fmaf(hv.x, wl.x, fmaf(hv.y, wl.y, fmaf(hv.z, wl.z, fmaf(hv.w, wl.w, pa[c]))));
      qa[c] = fmaf(hv.x, wr.x, fmaf(hv.y, wr.y, fmaf(hv.z, wr.z, fmaf(hv.w, wr.w, qa[c]))));
    }
  }

  float4* P4 = (float4*)(p2 + (size_t)node * 16);
  float4* Q4 = (float4*)(q2 + (size_t)node * 16);
  P4[0] = make_float4(pa[0], pa[1], pa[2], pa[3]);
  P4[1] = make_float4(pa[4], pa[5], pa[6], pa[7]);
  P4[2] = make_float4(pa[8], pa[9], 0.f, 0.f);
  P4[3] = make_float4(0.f, 0.f, 0.f, 0.f);
  Q4[0] = make_float4(qa[0] + bs[0], qa[1] + bs[1], qa[2] + bs[2], qa[3] + bs[3]);
  Q4[1] = make_float4(qa[4] + bs[4], qa[5] + bs[5], qa[6] + bs[6], qa[7] + bs[7]);
  Q4[2] = make_float4(qa[8] + bs[8], qa[9] + bs[9], 0.f, 0.f);
  Q4[3] = make_float4(0.f, 0.f, 0.f, 0.f);
}

// ---------------- layer-2 gather + l2norm + log_softmax -----------------------
// wave per node; 4 lanes per row (float4/lane over 16 padded cols), 16 edges/iter.
__global__ __launch_bounds__(256) void gather2_kernel(
    const int* __restrict__ row_ptr, const int* __restrict__ col,
    const float* __restrict__ p2, const float* __restrict__ q2,
    float* __restrict__ out, int N) {
  int tid = threadIdx.x;
  int wave = tid >> 6, lane = tid & 63;
  int g = lane >> 2, q = lane & 3;
  int node = blockIdx.x * 4 + wave;
  if (node >= N) return;

  int beg = row_ptr[node];
  int end = row_ptr[node + 1];
  const float4* P4 = (const float4*)p2;

  float4 acc = make_float4(0.f, 0.f, 0.f, 0.f);
  int e = beg + g;
  for (; e + 16 < end; e += 32) {  // 32 edges in flight per wave
    int s0 = col[e], s1 = col[e + 16];
    float4 v0 = P4[(size_t)s0 * 4 + q];
    float4 v1 = P4[(size_t)s1 * 4 + q];
    acc = f4add(acc, f4add(v0, v1));
  }
  if (e < end) {
    int s = col[e];
    acc = f4add(acc, P4[(size_t)s * 4 + q]);
  }

  // reduce across the 16 edge-groups (lane bits 2..5)
#pragma unroll
  for (int off = 4; off <= 32; off <<= 1) {
    acc.x += __shfl_xor(acc.x, off);
    acc.y += __shfl_xor(acc.y, off);
    acc.z += __shfl_xor(acc.z, off);
    acc.w += __shfl_xor(acc.w, off);
  }

  float invc = 1.0f / (float)max(end - beg, 1);
  float4 qv = ((const float4*)q2)[(size_t)node * 4 + q];
  float4 v = make_float4(fmaf(acc.x, invc, qv.x), fmaf(acc.y, invc, qv.y),
                         fmaf(acc.z, invc, qv.z), fmaf(acc.w, invc, qv.w));
  // padding cols (>=10) are exactly 0 in p2 and q2 -> v = 0 there

  float ss = v.x * v.x + v.y * v.y + v.z * v.z + v.w * v.w;
  ss += __shfl_xor(ss, 1);
  ss += __shfl_xor(ss, 2);
  float scale = 1.0f / fmaxf(sqrtf(ss), 1e-12f);
  v.x *= scale; v.y *= scale; v.z *= scale; v.w *= scale;

  float m;
  if (q < 2)       m = fmaxf(fmaxf(v.x, v.y), fmaxf(v.z, v.w));
  else if (q == 2) m = fmaxf(v.x, v.y);
  else             m = -1e30f;
  m = fmaxf(m, __shfl_xor(m, 1));
  m = fmaxf(m, __shfl_xor(m, 2));

  float es;
  if (q < 2)       es = __expf(v.x - m) + __expf(v.y - m) + __expf(v.z - m) + __expf(v.w - m);
  else if (q == 2) es = __expf(v.x - m) + __expf(v.y - m);
  else             es = 0.0f;
  es += __shfl_xor(es, 1);
  es += __shfl_xor(es, 2);
  float lse = m + __logf(es);

  if (g == 0 && q < 3) {
    float2* o = (float2*)(out + (size_t)node * 10);  // 8B-aligned always
    if (q < 2) {
      o[q * 2]     = make_float2(v.x - lse, v.y - lse);
      o[q * 2 + 1] = make_float2(v.z - lse, v.w - lse);
    } else {
      o[4] = make_float2(v.x - lse, v.y - lse);
    }
  }
}

extern "C" void kernel_launch(void* const* d_in, const int* in_sizes, int n_in,
                              void* d_out, int out_size, void* d_ws, size_t ws_size,
                              hipStream_t stream) {
  const float* features = (const float*)d_in[0];
  const int* edge_index = (const int*)d_in[1];
  const float* W1_l = (const float*)d_in[2];
  const float* b1   = (const float*)d_in[3];
  const float* W1_r = (const float*)d_in[4];
  const float* W2_l = (const float*)d_in[5];
  const float* b2   = (const float*)d_in[6];
  const float* W2_r = (const float*)d_in[7];
  float* out = (float*)d_out;

  const int N = in_sizes[0] / FEAT;    // 50000
  const int E = in_sizes[1] / 2;       // 1250000
  const int* src = edge_index;
  const int* dst = edge_index + E;

  char* ws = (char*)d_ws;
  int* deg      = (int*)(ws + 0);
  int* partials = (int*)(ws + 200000);
  int* row_ptr  = (int*)(ws + 200256);
  int* cursor   = (int*)(ws + 400272);
  int* col      = (int*)(ws + 600272);
  float* p1     = (float*)(ws + 5600272);
  float* q1h1   = (float*)(ws + 18400272);
  float* p2     = (float*)(ws + 31200272);
  float* q2     = (float*)(ws + 34400272);

  hipMemsetAsync(deg, 0, (size_t)N * sizeof(int), stream);

  int eb = (E + 255) / 256;
  int nb1024 = (N + 1023) / 1024;  // 49 (<=64 supported by scan_partials)
  int nb256 = (N + 255) / 256;     // 196
  int nbw = (N + 3) / 4;           // 12500

  hist_kernel<<<eb, 256, 0, stream>>>(dst, deg, E);
  partial_sum_kernel<<<nb1024, 1024, 0, stream>>>(deg, partials, N);
  scan_partials_kernel<<<1, 64, 0, stream>>>(partials, nb1024);
  scan_tile_kernel<<<nb1024, 1024, 0, stream>>>(deg, partials, row_ptr, cursor, N, E);
  fill_kernel<<<eb, 256, 0, stream>>>(src, dst, cursor, col, E);

  dense1_kernel<<<dim3(nb256, 8), 256, 0, stream>>>(features, W1_l, W1_r, b1, p1, q1h1, N);
  gather1_kernel<<<nbw, 256, 0, stream>>>(row_ptr, col, p1, q1h1, N);
  dense2_kernel<<<nb256, 256, 0, stream>>>(q1h1, W2_l, W2_r, b2, p2, q2, N);
  gather2_kernel<<<nbw, 256, 0, stream>>>(row_ptr, col, p2, q2, out, N);
}

// Round 4
// 340.100 us; speedup vs baseline: 6.6444x; 1.4487x over previous
//
#include <hip/hip_runtime.h>

// GraphSAGE 2-layer forward, f32. Linearity trick: aggregate AFTER the dense
// transform (mean(x_j)@W^T == mean(x_j@W^T)), so gathers are pure memory ops.
// N=50000, feat=hid=64, nclass=10 (padded to 16), E=1.25M.
// R4: dense kernels restructured to kill register spill (R3: VGPR=256,
//     317 MB scratch writes). x-row preloaded to regs, bounded unroll.
//
// ws layout (bytes):
//   deg      [N]     int   @ 0
//   partials [64]    int   @ 200000
//   row_ptr  [N+1]   int   @ 200256
//   cursor   [N]     int   @ 400272
//   col      [E]     int   @ 600272
//   p1       [N*64]  f32   @ 5600272   (x @ W1_l^T)
//   q1h1     [N*64]  f32   @ 18400272  (x @ W1_r^T + b1, overwritten by h1)
//   p2       [N*16]  f32   @ 31200272  (h1 @ W2_l^T, cols 10..15 = 0)
//   q2       [N*16]  f32   @ 34400272  (h1 @ W2_r^T + b2, cols 10..15 = 0)

static constexpr int FEAT = 64;

__device__ __forceinline__ float4 f4add(float4 a, float4 b) {
  return make_float4(a.x + b.x, a.y + b.y, a.z + b.z, a.w + b.w);
}

// ---------------- CSR build ----------------
__global__ __launch_bounds__(256) void hist_kernel(
    const int* __restrict__ dst, int* __restrict__ deg, int E) {
  int e = blockIdx.x * 256 + threadIdx.x;
  if (e < E) atomicAdd(&deg[dst[e]], 1);
}

__global__ __launch_bounds__(1024) void partial_sum_kernel(
    const int* __restrict__ deg, int* __restrict__ partials, int N) {
  __shared__ int ws[16];
  int i = blockIdx.x * 1024 + threadIdx.x;
  int v = (i < N) ? deg[i] : 0;
#pragma unroll
  for (int off = 32; off; off >>= 1) v += __shfl_xor(v, off);
  int w = threadIdx.x >> 6, lane = threadIdx.x & 63;
  if (lane == 0) ws[w] = v;
  __syncthreads();
  if (threadIdx.x == 0) {
    int s = 0;
#pragma unroll
    for (int k = 0; k < 16; ++k) s += ws[k];
    partials[blockIdx.x] = s;
  }
}

__global__ __launch_bounds__(64) void scan_partials_kernel(
    int* __restrict__ partials, int nb) {
  int t = threadIdx.x;
  int orig = (t < nb) ? partials[t] : 0;
  int v = orig;
#pragma unroll
  for (int off = 1; off < 64; off <<= 1) {
    int u = __shfl_up(v, off);
    if (t >= off) v += u;
  }
  if (t < nb) partials[t] = v - orig;  // exclusive
}

__global__ __launch_bounds__(1024) void scan_tile_kernel(
    const int* __restrict__ deg, const int* __restrict__ partials,
    int* __restrict__ row_ptr, int* __restrict__ cursor, int N, int E) {
  __shared__ int ws[16];
  int tid = threadIdx.x;
  int i = blockIdx.x * 1024 + tid;
  int d = (i < N) ? deg[i] : 0;
  int v = d;
  int lane = tid & 63, w = tid >> 6;
#pragma unroll
  for (int off = 1; off < 64; off <<= 1) {
    int u = __shfl_up(v, off);
    if (lane >= off) v += u;
  }
  if (lane == 63) ws[w] = v;
  __syncthreads();
  if (w == 0) {
    int s = (lane < 16) ? ws[lane] : 0;
#pragma unroll
    for (int off = 1; off < 16; off <<= 1) {
      int u = __shfl_up(s, off);
      if (lane >= off) s += u;
    }
    if (lane < 16) ws[lane] = s;  // inclusive over waves
  }
  __syncthreads();
  int woff = (w == 0) ? 0 : ws[w - 1];
  int ex = partials[blockIdx.x] + woff + v - d;
  if (i < N) { row_ptr[i] = ex; cursor[i] = ex; }
  if (i == 0) row_ptr[N] = E;
}

__global__ __launch_bounds__(256) void fill_kernel(
    const int* __restrict__ src, const int* __restrict__ dst,
    int* __restrict__ cursor, int* __restrict__ col, int E) {
  int e = blockIdx.x * 256 + threadIdx.x;
  if (e >= E) return;
  int pos = atomicAdd(&cursor[dst[e]], 1);
  col[pos] = src[e];
}

// ---------------- layer-1 dense: p1 = x@Wl^T, q1 = x@Wr^T + b ----------------
// grid (ceil(N/256), 8): y>>2 = mat (0:Wl->p, 1:Wr->q), y&3 = out-group of 16.
// x-row preloaded to 16 float4 regs; o-loop unroll-bounded to avoid spill.
__global__ __launch_bounds__(256) void dense1_kernel(
    const float* __restrict__ x,
    const float* __restrict__ Wl, const float* __restrict__ Wr,
    const float* __restrict__ b,
    float* __restrict__ p, float* __restrict__ q, int N) {
  __shared__ float4 Ws[16 * 16];  // 16 output rows x 16 k-quads
  int mat = blockIdx.y >> 2;
  int og = blockIdx.y & 3;
  const float4* Wg = (const float4*)(mat ? Wr : Wl);
  int tid = threadIdx.x;
  Ws[tid] = Wg[(og * 16) * 16 + tid];  // 256 float4 = exactly blockDim
  __syncthreads();

  int node = blockIdx.x * 256 + tid;
  if (node >= N) return;

  const float4* X4 = (const float4*)x + (size_t)node * 16;
  float4 xr[16];
#pragma unroll
  for (int kq = 0; kq < 16; ++kq) xr[kq] = X4[kq];

  float acc[16];
#pragma unroll 4
  for (int o = 0; o < 16; ++o) {
    float a = 0.0f;
#pragma unroll
    for (int kq = 0; kq < 16; ++kq) {
      float4 w = Ws[o * 16 + kq];  // uniform address -> LDS broadcast
      float4 xv = xr[kq];
      a = fmaf(xv.x, w.x, fmaf(xv.y, w.y, fmaf(xv.z, w.z, fmaf(xv.w, w.w, a))));
    }
    acc[o] = a;
  }

  float4* O4 = (float4*)((mat ? q : p) + (size_t)node * FEAT + og * 16);
  const float4* B4 = (const float4*)(b + og * 16);
#pragma unroll
  for (int oq = 0; oq < 4; ++oq) {
    float4 v = make_float4(acc[oq * 4], acc[oq * 4 + 1], acc[oq * 4 + 2], acc[oq * 4 + 3]);
    if (mat) { float4 bv = B4[oq]; v = f4add(v, bv); }
    O4[oq] = v;
  }
}

// ---------------- layer-1 gather: h = relu(l2norm(mean(p)+q)), in-place to q --
// wave per node; 16 lanes per row (float4/lane), 4 edges per iteration.
__global__ __launch_bounds__(256) void gather1_kernel(
    const int* __restrict__ row_ptr, const int* __restrict__ col,
    const float* __restrict__ p, float* __restrict__ qh, int N) {
  int tid = threadIdx.x;
  int wave = tid >> 6, lane = tid & 63;
  int g = lane >> 4, q = lane & 15;
  int node = blockIdx.x * 4 + wave;
  if (node >= N) return;

  int beg = row_ptr[node];
  int end = row_ptr[node + 1];
  const float4* P4 = (const float4*)p;

  float4 acc = make_float4(0.f, 0.f, 0.f, 0.f);
  int e = beg + g;
  for (; e + 4 < end; e += 8) {  // 8 edges in flight per wave
    int s0 = col[e], s1 = col[e + 4];
    float4 v0 = P4[(size_t)s0 * 16 + q];
    float4 v1 = P4[(size_t)s1 * 16 + q];
    acc = f4add(acc, f4add(v0, v1));
  }
  if (e < end) {
    int s = col[e];
    acc = f4add(acc, P4[(size_t)s * 16 + q]);
  }

  // reduce across the 4 edge-groups (lane bits 4,5)
#pragma unroll
  for (int off = 16; off <= 32; off <<= 1) {
    acc.x += __shfl_xor(acc.x, off);
    acc.y += __shfl_xor(acc.y, off);
    acc.z += __shfl_xor(acc.z, off);
    acc.w += __shfl_xor(acc.w, off);
  }

  float invc = 1.0f / (float)max(end - beg, 1);
  float4 qv = ((const float4*)qh)[(size_t)node * 16 + q];
  float4 v = make_float4(fmaf(acc.x, invc, qv.x), fmaf(acc.y, invc, qv.y),
                         fmaf(acc.z, invc, qv.z), fmaf(acc.w, invc, qv.w));

  float ss = v.x * v.x + v.y * v.y + v.z * v.z + v.w * v.w;
#pragma unroll
  for (int off = 1; off <= 8; off <<= 1) ss += __shfl_xor(ss, off);
  float scale = 1.0f / fmaxf(sqrtf(ss), 1e-12f);

  v.x = fmaxf(v.x * scale, 0.0f);
  v.y = fmaxf(v.y * scale, 0.0f);
  v.z = fmaxf(v.z * scale, 0.0f);
  v.w = fmaxf(v.w * scale, 0.0f);
  if (g == 0) ((float4*)qh)[(size_t)node * 16 + q] = v;  // in-place h
}

// ---------------- layer-2 dense: p2 = h@W2l^T, q2 = h@W2r^T + b2 (pad to 16) --
__global__ __launch_bounds__(256) void dense2_kernel(
    const float* __restrict__ h,
    const float* __restrict__ Wl, const float* __restrict__ Wr,
    const float* __restrict__ b,
    float* __restrict__ p2, float* __restrict__ q2, int N) {
  __shared__ float4 Wls[10 * 16];
  __shared__ float4 Wrs[10 * 16];
  __shared__ float bs[10];
  int tid = threadIdx.x;
  if (tid < 160) {
    Wls[tid] = ((const float4*)Wl)[tid];
    Wrs[tid] = ((const float4*)Wr)[tid];
  }
  if (tid < 10) bs[tid] = b[tid];
  __syncthreads();

  int node = blockIdx.x * 256 + tid;
  if (node >= N) return;

  const float4* H4 = (const float4*)h + (size_t)node * 16;
  float4 hr[16];
#pragma unroll
  for (int kq = 0; kq < 16; ++kq) hr[kq] = H4[kq];

  float pa[10], qa[10];
#pragma unroll 1
  for (int c = 0; c < 10; ++c) {
    float ap = 0.0f, aq = 0.0f;
#pragma unroll
    for (int kq = 0; kq < 16; ++kq) {
      float4 wl = Wls[c * 16 + kq];
      float4 wr = Wrs[c * 16 + kq];
      float4 hv = hr[kq];
      ap = fmaf(hv.x, wl.x, fmaf(hv.y, wl.y, fmaf(hv.z, wl.z, fmaf(hv.w, wl.w, ap))));
      aq = fmaf(hv.x, wr.x, fmaf(hv.y, wr.y, fmaf(hv.z, wr.z, fmaf(hv.w, wr.w, aq))));
    }
    pa[c] = ap;
    qa[c] = aq;
  }

  float4* P4 = (float4*)(p2 + (size_t)node * 16);
  float4* Q4 = (float4*)(q2 + (size_t)node * 16);
  P4[0] = make_float4(pa[0], pa[1], pa[2], pa[3]);
  P4[1] = make_float4(pa[4], pa[5], pa[6], pa[7]);
  P4[2] = make_float4(pa[8], pa[9], 0.f, 0.f);
  P4[3] = make_float4(0.f, 0.f, 0.f, 0.f);
  Q4[0] = make_float4(qa[0] + bs[0], qa[1] + bs[1], qa[2] + bs[2], qa[3] + bs[3]);
  Q4[1] = make_float4(qa[4] + bs[4], qa[5] + bs[5], qa[6] + bs[6], qa[7] + bs[7]);
  Q4[2] = make_float4(qa[8] + bs[8], qa[9] + bs[9], 0.f, 0.f);
  Q4[3] = make_float4(0.f, 0.f, 0.f, 0.f);
}

// ---------------- layer-2 gather + l2norm + log_softmax -----------------------
// wave per node; 4 lanes per row (float4/lane over 16 padded cols), 16 edges/iter.
__global__ __launch_bounds__(256) void gather2_kernel(
    const int* __restrict__ row_ptr, const int* __restrict__ col,
    const float* __restrict__ p2, const float* __restrict__ q2,
    float* __restrict__ out, int N) {
  int tid = threadIdx.x;
  int wave = tid >> 6, lane = tid & 63;
  int g = lane >> 2, q = lane & 3;
  int node = blockIdx.x * 4 + wave;
  if (node >= N) return;

  int beg = row_ptr[node];
  int end = row_ptr[node + 1];
  const float4* P4 = (const float4*)p2;

  float4 acc = make_float4(0.f, 0.f, 0.f, 0.f);
  int e = beg + g;
  for (; e + 16 < end; e += 32) {  // 32 edges in flight per wave
    int s0 = col[e], s1 = col[e + 16];
    float4 v0 = P4[(size_t)s0 * 4 + q];
    float4 v1 = P4[(size_t)s1 * 4 + q];
    acc = f4add(acc, f4add(v0, v1));
  }
  if (e < end) {
    int s = col[e];
    acc = f4add(acc, P4[(size_t)s * 4 + q]);
  }

  // reduce across the 16 edge-groups (lane bits 2..5)
#pragma unroll
  for (int off = 4; off <= 32; off <<= 1) {
    acc.x += __shfl_xor(acc.x, off);
    acc.y += __shfl_xor(acc.y, off);
    acc.z += __shfl_xor(acc.z, off);
    acc.w += __shfl_xor(acc.w, off);
  }

  float invc = 1.0f / (float)max(end - beg, 1);
  float4 qv = ((const float4*)q2)[(size_t)node * 4 + q];
  float4 v = make_float4(fmaf(acc.x, invc, qv.x), fmaf(acc.y, invc, qv.y),
                         fmaf(acc.z, invc, qv.z), fmaf(acc.w, invc, qv.w));
  // padding cols (>=10) are exactly 0 in p2 and q2 -> v = 0 there

  float ss = v.x * v.x + v.y * v.y + v.z * v.z + v.w * v.w;
  ss += __shfl_xor(ss, 1);
  ss += __shfl_xor(ss, 2);
  float scale = 1.0f / fmaxf(sqrtf(ss), 1e-12f);
  v.x *= scale; v.y *= scale; v.z *= scale; v.w *= scale;

  float m;
  if (q < 2)       m = fmaxf(fmaxf(v.x, v.y), fmaxf(v.z, v.w));
  else if (q == 2) m = fmaxf(v.x, v.y);
  else             m = -1e30f;
  m = fmaxf(m, __shfl_xor(m, 1));
  m = fmaxf(m, __shfl_xor(m, 2));

  float es;
  if (q < 2)       es = __expf(v.x - m) + __expf(v.y - m) + __expf(v.z - m) + __expf(v.w - m);
  else if (q == 2) es = __expf(v.x - m) + __expf(v.y - m);
  else             es = 0.0f;
  es += __shfl_xor(es, 1);
  es += __shfl_xor(es, 2);
  float lse = m + __logf(es);

  if (g == 0 && q < 3) {
    float2* o = (float2*)(out + (size_t)node * 10);  // 8B-aligned always
    if (q < 2) {
      o[q * 2]     = make_float2(v.x - lse, v.y - lse);
      o[q * 2 + 1] = make_float2(v.z - lse, v.w - lse);
    } else {
      o[4] = make_float2(v.x - lse, v.y - lse);
    }
  }
}

extern "C" void kernel_launch(void* const* d_in, const int* in_sizes, int n_in,
                              void* d_out, int out_size, void* d_ws, size_t ws_size,
                              hipStream_t stream) {
  const float* features = (const float*)d_in[0];
  const int* edge_index = (const int*)d_in[1];
  const float* W1_l = (const float*)d_in[2];
  const float* b1   = (const float*)d_in[3];
  const float* W1_r = (const float*)d_in[4];
  const float* W2_l = (const float*)d_in[5];
  const float* b2   = (const float*)d_in[6];
  const float* W2_r = (const float*)d_in[7];
  float* out = (float*)d_out;

  const int N = in_sizes[0] / FEAT;    // 50000
  const int E = in_sizes[1] / 2;       // 1250000
  const int* src = edge_index;
  const int* dst = edge_index + E;

  char* ws = (char*)d_ws;
  int* deg      = (int*)(ws + 0);
  int* partials = (int*)(ws + 200000);
  int* row_ptr  = (int*)(ws + 200256);
  int* cursor   = (int*)(ws + 400272);
  int* col      = (int*)(ws + 600272);
  float* p1     = (float*)(ws + 5600272);
  float* q1h1   = (float*)(ws + 18400272);
  float* p2     = (float*)(ws + 31200272);
  float* q2     = (float*)(ws + 34400272);

  hipMemsetAsync(deg, 0, (size_t)N * sizeof(int), stream);

  int eb = (E + 255) / 256;
  int nb1024 = (N + 1023) / 1024;  // 49
  int nb256 = (N + 255) / 256;     // 196
  int nbw = (N + 3) / 4;           // 12500

  hist_kernel<<<eb, 256, 0, stream>>>(dst, deg, E);
  partial_sum_kernel<<<nb1024, 1024, 0, stream>>>(deg, partials, N);
  scan_partials_kernel<<<1, 64, 0, stream>>>(partials, nb1024);
  scan_tile_kernel<<<nb1024, 1024, 0, stream>>>(deg, partials, row_ptr, cursor, N, E);
  fill_kernel<<<eb, 256, 0, stream>>>(src, dst, cursor, col, E);

  dense1_kernel<<<dim3(nb256, 8), 256, 0, stream>>>(features, W1_l, W1_r, b1, p1, q1h1, N);
  gather1_kernel<<<nbw, 256, 0, stream>>>(row_ptr, col, p1, q1h1, N);
  dense2_kernel<<<nb256, 256, 0, stream>>>(q1h1, W2_l, W2_r, b2, p2, q2, N);
  gather2_kernel<<<nbw, 256, 0, stream>>>(row_ptr, col, p2, q2, out, N);
}

// Round 5
// 289.253 us; speedup vs baseline: 7.8124x; 1.1758x over previous
//
#include <hip/hip_runtime.h>
#include <hip/hip_bf16.h>

// GraphSAGE 2-layer forward. Linearity trick: aggregate AFTER the dense
// transform (mean(x_j)@W^T == mean(x_j@W^T)), so gathers are pure memory ops.
// N=50000, feat=hid=64, nclass=10 (padded to 16), E=1.25M.
// R5: (1) fill/hist XCD-bucketed (dst-range filter, blockIdx&7 -> XCD) to kill
//     partial-line writebacks (R4: WRITE_SIZE 83MB for 5MB payload);
//     (2) p1 stored bf16 -> gather1 traffic halved (320->160MB).
//
// ws layout (bytes):
//   deg      [N]     int   @ 0
//   partials [64]    int   @ 200000
//   row_ptr  [N+1]   int   @ 200256
//   cursor   [N]     int   @ 400272
//   col      [E]     int   @ 600272
//   p1       [N*64]  bf16  @ 5600272   (x @ W1_l^T, rounded RNE)
//   q1h1     [N*64]  f32   @ 12000272  (x @ W1_r^T + b1, overwritten by h1)
//   p2       [N*16]  f32   @ 24800272  (h1 @ W2_l^T, cols 10..15 = 0)
//   q2       [N*16]  f32   @ 28000272  (h1 @ W2_r^T + b2, cols 10..15 = 0)

static constexpr int FEAT = 64;
static constexpr int NBUCK = 8;        // XCD count
static constexpr int BUCK_SZ = 6250;   // 50000 / 8

__device__ __forceinline__ float4 f4add(float4 a, float4 b) {
  return make_float4(a.x + b.x, a.y + b.y, a.z + b.z, a.w + b.w);
}
__device__ __forceinline__ unsigned short f2bf(float f) {
  __hip_bfloat16 h = __float2bfloat16(f);
  return *reinterpret_cast<unsigned short*>(&h);
}
__device__ __forceinline__ float bfl(unsigned int u) {
  return __uint_as_float(u << 16);
}
__device__ __forceinline__ float bfh(unsigned int u) {
  return __uint_as_float(u & 0xFFFF0000u);
}

// ---------------- CSR build ----------------
// XCD-bucketed histogram: block (chunk, b) counts only dst in bucket b, so
// each deg cache line is owned by one XCD's L2.
__global__ __launch_bounds__(256) void hist_kernel(
    const int* __restrict__ dst, int* __restrict__ deg, int E) {
  int b = blockIdx.x & 7;
  int e = (blockIdx.x >> 3) * 256 + threadIdx.x;
  if (e >= E) return;
  int d = dst[e];
  int lo = b * BUCK_SZ;
  if (d >= lo && d < lo + BUCK_SZ) atomicAdd(&deg[d], 1);
}

__global__ __launch_bounds__(1024) void partial_sum_kernel(
    const int* __restrict__ deg, int* __restrict__ partials, int N) {
  __shared__ int ws[16];
  int i = blockIdx.x * 1024 + threadIdx.x;
  int v = (i < N) ? deg[i] : 0;
#pragma unroll
  for (int off = 32; off; off >>= 1) v += __shfl_xor(v, off);
  int w = threadIdx.x >> 6, lane = threadIdx.x & 63;
  if (lane == 0) ws[w] = v;
  __syncthreads();
  if (threadIdx.x == 0) {
    int s = 0;
#pragma unroll
    for (int k = 0; k < 16; ++k) s += ws[k];
    partials[blockIdx.x] = s;
  }
}

__global__ __launch_bounds__(64) void scan_partials_kernel(
    int* __restrict__ partials, int nb) {
  int t = threadIdx.x;
  int orig = (t < nb) ? partials[t] : 0;
  int v = orig;
#pragma unroll
  for (int off = 1; off < 64; off <<= 1) {
    int u = __shfl_up(v, off);
    if (t >= off) v += u;
  }
  if (t < nb) partials[t] = v - orig;  // exclusive
}

__global__ __launch_bounds__(1024) void scan_tile_kernel(
    const int* __restrict__ deg, const int* __restrict__ partials,
    int* __restrict__ row_ptr, int* __restrict__ cursor, int N, int E) {
  __shared__ int ws[16];
  int tid = threadIdx.x;
  int i = blockIdx.x * 1024 + tid;
  int d = (i < N) ? deg[i] : 0;
  int v = d;
  int lane = tid & 63, w = tid >> 6;
#pragma unroll
  for (int off = 1; off < 64; off <<= 1) {
    int u = __shfl_up(v, off);
    if (lane >= off) v += u;
  }
  if (lane == 63) ws[w] = v;
  __syncthreads();
  if (w == 0) {
    int s = (lane < 16) ? ws[lane] : 0;
#pragma unroll
    for (int off = 1; off < 16; off <<= 1) {
      int u = __shfl_up(s, off);
      if (lane >= off) s += u;
    }
    if (lane < 16) ws[lane] = s;  // inclusive over waves
  }
  __syncthreads();
  int woff = (w == 0) ? 0 : ws[w - 1];
  int ex = partials[blockIdx.x] + woff + v - d;
  if (i < N) { row_ptr[i] = ex; cursor[i] = ex; }
  if (i == 0) row_ptr[N] = E;
}

// XCD-bucketed counting-sort fill: block (chunk, b) only places edges whose
// dst is in bucket b -> col lines single-XCD-owned -> full-line writebacks.
__global__ __launch_bounds__(256) void fill_kernel(
    const int* __restrict__ src, const int* __restrict__ dst,
    int* __restrict__ cursor, int* __restrict__ col, int E) {
  int b = blockIdx.x & 7;
  int e = (blockIdx.x >> 3) * 256 + threadIdx.x;
  if (e >= E) return;
  int d = dst[e];
  int s = src[e];
  int lo = b * BUCK_SZ;
  if (d >= lo && d < lo + BUCK_SZ) {
    int pos = atomicAdd(&cursor[d], 1);
    col[pos] = s;
  }
}

// ---------------- layer-1 dense: p1 = bf16(x@Wl^T), q1 = x@Wr^T + b ----------
// grid (ceil(N/256), 8): y>>2 = mat (0:Wl->p, 1:Wr->q), y&3 = out-group of 16.
__global__ __launch_bounds__(256) void dense1_kernel(
    const float* __restrict__ x,
    const float* __restrict__ Wl, const float* __restrict__ Wr,
    const float* __restrict__ b,
    unsigned short* __restrict__ p, float* __restrict__ q, int N) {
  __shared__ float4 Ws[16 * 16];  // 16 output rows x 16 k-quads
  int mat = blockIdx.y >> 2;
  int og = blockIdx.y & 3;
  const float4* Wg = (const float4*)(mat ? Wr : Wl);
  int tid = threadIdx.x;
  Ws[tid] = Wg[(og * 16) * 16 + tid];  // 256 float4 = exactly blockDim
  __syncthreads();

  int node = blockIdx.x * 256 + tid;
  if (node >= N) return;

  const float4* X4 = (const float4*)x + (size_t)node * 16;
  float4 xr[16];
#pragma unroll
  for (int kq = 0; kq < 16; ++kq) xr[kq] = X4[kq];

  float acc[16];
#pragma unroll 4
  for (int o = 0; o < 16; ++o) {
    float a = 0.0f;
#pragma unroll
    for (int kq = 0; kq < 16; ++kq) {
      float4 w = Ws[o * 16 + kq];  // uniform address -> LDS broadcast
      float4 xv = xr[kq];
      a = fmaf(xv.x, w.x, fmaf(xv.y, w.y, fmaf(xv.z, w.z, fmaf(xv.w, w.w, a))));
    }
    acc[o] = a;
  }

  if (mat) {
    float4* O4 = (float4*)(q + (size_t)node * FEAT + og * 16);
    const float4* B4 = (const float4*)(b + og * 16);
#pragma unroll
    for (int oq = 0; oq < 4; ++oq) {
      float4 bv = B4[oq];
      O4[oq] = make_float4(acc[oq * 4] + bv.x, acc[oq * 4 + 1] + bv.y,
                           acc[oq * 4 + 2] + bv.z, acc[oq * 4 + 3] + bv.w);
    }
  } else {
    // pack 16 bf16 = 32 B = 2 uint4
    uint4 w0, w1;
    w0.x = f2bf(acc[0]) | ((unsigned)f2bf(acc[1]) << 16);
    w0.y = f2bf(acc[2]) | ((unsigned)f2bf(acc[3]) << 16);
    w0.z = f2bf(acc[4]) | ((unsigned)f2bf(acc[5]) << 16);
    w0.w = f2bf(acc[6]) | ((unsigned)f2bf(acc[7]) << 16);
    w1.x = f2bf(acc[8]) | ((unsigned)f2bf(acc[9]) << 16);
    w1.y = f2bf(acc[10]) | ((unsigned)f2bf(acc[11]) << 16);
    w1.z = f2bf(acc[12]) | ((unsigned)f2bf(acc[13]) << 16);
    w1.w = f2bf(acc[14]) | ((unsigned)f2bf(acc[15]) << 16);
    uint4* O = (uint4*)p + (size_t)node * 8 + og * 2;
    O[0] = w0;
    O[1] = w1;
  }
}

// ---------------- layer-1 gather: h = relu(l2norm(mean(p)+q)), into q --------
// wave per node; bf16 rows = 128 B = 8 lanes x uint4; 16 edges in flight.
__global__ __launch_bounds__(256) void gather1_kernel(
    const int* __restrict__ row_ptr, const int* __restrict__ col,
    const uint4* __restrict__ p1, float* __restrict__ qh, int N) {
  int tid = threadIdx.x;
  int wave = tid >> 6, lane = tid & 63;
  int g = lane >> 3, q = lane & 7;  // 8 edge-groups x 8 lanes/row
  int node = blockIdx.x * 4 + wave;
  if (node >= N) return;

  int beg = row_ptr[node];
  int end = row_ptr[node + 1];

  float a[8];
#pragma unroll
  for (int j = 0; j < 8; ++j) a[j] = 0.0f;

  int e = beg + g;
  for (; e + 8 < end; e += 16) {  // 16 edges in flight per wave
    int s0 = col[e], s1 = col[e + 8];
    uint4 w0 = p1[(size_t)s0 * 8 + q];
    uint4 w1 = p1[(size_t)s1 * 8 + q];
    a[0] += bfl(w0.x); a[1] += bfh(w0.x); a[2] += bfl(w0.y); a[3] += bfh(w0.y);
    a[4] += bfl(w0.z); a[5] += bfh(w0.z); a[6] += bfl(w0.w); a[7] += bfh(w0.w);
    a[0] += bfl(w1.x); a[1] += bfh(w1.x); a[2] += bfl(w1.y); a[3] += bfh(w1.y);
    a[4] += bfl(w1.z); a[5] += bfh(w1.z); a[6] += bfl(w1.w); a[7] += bfh(w1.w);
  }
  if (e < end) {
    uint4 w0 = p1[(size_t)col[e] * 8 + q];
    a[0] += bfl(w0.x); a[1] += bfh(w0.x); a[2] += bfl(w0.y); a[3] += bfh(w0.y);
    a[4] += bfl(w0.z); a[5] += bfh(w0.z); a[6] += bfl(w0.w); a[7] += bfh(w0.w);
  }

  // reduce across the 8 edge-groups (lane bits 3..5)
#pragma unroll
  for (int off = 8; off <= 32; off <<= 1) {
#pragma unroll
    for (int j = 0; j < 8; ++j) a[j] += __shfl_xor(a[j], off);
  }

  float invc = 1.0f / (float)max(end - beg, 1);
  const float4* Q4 = (const float4*)qh + (size_t)node * 16 + q * 2;
  float4 q0 = Q4[0], q1 = Q4[1];
  float v[8];
  v[0] = fmaf(a[0], invc, q0.x); v[1] = fmaf(a[1], invc, q0.y);
  v[2] = fmaf(a[2], invc, q0.z); v[3] = fmaf(a[3], invc, q0.w);
  v[4] = fmaf(a[4], invc, q1.x); v[5] = fmaf(a[5], invc, q1.y);
  v[6] = fmaf(a[6], invc, q1.z); v[7] = fmaf(a[7], invc, q1.w);

  float ss = 0.0f;
#pragma unroll
  for (int j = 0; j < 8; ++j) ss += v[j] * v[j];
#pragma unroll
  for (int off = 1; off <= 4; off <<= 1) ss += __shfl_xor(ss, off);
  float scale = 1.0f / fmaxf(sqrtf(ss), 1e-12f);

  if (g == 0) {
    float4* O4 = (float4*)qh + (size_t)node * 16 + q * 2;
    O4[0] = make_float4(fmaxf(v[0] * scale, 0.f), fmaxf(v[1] * scale, 0.f),
                        fmaxf(v[2] * scale, 0.f), fmaxf(v[3] * scale, 0.f));
    O4[1] = make_float4(fmaxf(v[4] * scale, 0.f), fmaxf(v[5] * scale, 0.f),
                        fmaxf(v[6] * scale, 0.f), fmaxf(v[7] * scale, 0.f));
  }
}

// ---------------- layer-2 dense: p2 = h@W2l^T, q2 = h@W2r^T + b2 (pad to 16) --
__global__ __launch_bounds__(256) void dense2_kernel(
    const float* __restrict__ h,
    const float* __restrict__ Wl, const float* __restrict__ Wr,
    const float* __restrict__ b,
    float* __restrict__ p2, float* __restrict__ q2, int N) {
  __shared__ float4 Wls[10 * 16];
  __shared__ float4 Wrs[10 * 16];
  __shared__ float bs[10];
  int tid = threadIdx.x;
  if (tid < 160) {
    Wls[tid] = ((const float4*)Wl)[tid];
    Wrs[tid] = ((const float4*)Wr)[tid];
  }
  if (tid < 10) bs[tid] = b[tid];
  __syncthreads();

  int node = blockIdx.x * 256 + tid;
  if (node >= N) return;

  const float4* H4 = (const float4*)h + (size_t)node * 16;
  float4 hr[16];
#pragma unroll
  for (int kq = 0; kq < 16; ++kq) hr[kq] = H4[kq];

  float pa[10], qa[10];
#pragma unroll 1
  for (int c = 0; c < 10; ++c) {
    float ap = 0.0f, aq = 0.0f;
#pragma unroll
    for (int kq = 0; kq < 16; ++kq) {
      float4 wl = Wls[c * 16 + kq];
      float4 wr = Wrs[c * 16 + kq];
      float4 hv = hr[kq];
      ap = fmaf(hv.x, wl.x, fmaf(hv.y, wl.y, fmaf(hv.z, wl.z, fmaf(hv.w, wl.w, ap))));
      aq = fmaf(hv.x, wr.x, fmaf(hv.y, wr.y, fmaf(hv.z, wr.z, fmaf(hv.w, wr.w, aq))));
    }
    pa[c] = ap;
    qa[c] = aq;
  }

  float4* P4 = (float4*)(p2 + (size_t)node * 16);
  float4* Q4 = (float4*)(q2 + (size_t)node * 16);
  P4[0] = make_float4(pa[0], pa[1], pa[2], pa[3]);
  P4[1] = make_float4(pa[4], pa[5], pa[6], pa[7]);
  P4[2] = make_float4(pa[8], pa[9], 0.f, 0.f);
  P4[3] = make_float4(0.f, 0.f, 0.f, 0.f);
  Q4[0] = make_float4(qa[0] + bs[0], qa[1] + bs[1], qa[2] + bs[2], qa[3] + bs[3]);
  Q4[1] = make_float4(qa[4] + bs[4], qa[5] + bs[5], qa[6] + bs[6], qa[7] + bs[7]);
  Q4[2] = make_float4(qa[8] + bs[8], qa[9] + bs[9], 0.f, 0.f);
  Q4[3] = make_float4(0.f, 0.f, 0.f, 0.f);
}

// ---------------- layer-2 gather + l2norm + log_softmax -----------------------
__global__ __launch_bounds__(256) void gather2_kernel(
    const int* __restrict__ row_ptr, const int* __restrict__ col,
    const float* __restrict__ p2, const float* __restrict__ q2,
    float* __restrict__ out, int N) {
  int tid = threadIdx.x;
  int wave = tid >> 6, lane = tid & 63;
  int g = lane >> 2, q = lane & 3;
  int node = blockIdx.x * 4 + wave;
  if (node >= N) return;

  int beg = row_ptr[node];
  int end = row_ptr[node + 1];
  const float4* P4 = (const float4*)p2;

  float4 acc = make_float4(0.f, 0.f, 0.f, 0.f);
  int e = beg + g;
  for (; e + 16 < end; e += 32) {  // 32 edges in flight per wave
    int s0 = col[e], s1 = col[e + 16];
    float4 v0 = P4[(size_t)s0 * 4 + q];
    float4 v1 = P4[(size_t)s1 * 4 + q];
    acc = f4add(acc, f4add(v0, v1));
  }
  if (e < end) {
    int s = col[e];
    acc = f4add(acc, P4[(size_t)s * 4 + q]);
  }

#pragma unroll
  for (int off = 4; off <= 32; off <<= 1) {
    acc.x += __shfl_xor(acc.x, off);
    acc.y += __shfl_xor(acc.y, off);
    acc.z += __shfl_xor(acc.z, off);
    acc.w += __shfl_xor(acc.w, off);
  }

  float invc = 1.0f / (float)max(end - beg, 1);
  float4 qv = ((const float4*)q2)[(size_t)node * 4 + q];
  float4 v = make_float4(fmaf(acc.x, invc, qv.x), fmaf(acc.y, invc, qv.y),
                         fmaf(acc.z, invc, qv.z), fmaf(acc.w, invc, qv.w));
  // padding cols (>=10) are exactly 0 in p2 and q2 -> v = 0 there

  float ss = v.x * v.x + v.y * v.y + v.z * v.z + v.w * v.w;
  ss += __shfl_xor(ss, 1);
  ss += __shfl_xor(ss, 2);
  float scale = 1.0f / fmaxf(sqrtf(ss), 1e-12f);
  v.x *= scale; v.y *= scale; v.z *= scale; v.w *= scale;

  float m;
  if (q < 2)       m = fmaxf(fmaxf(v.x, v.y), fmaxf(v.z, v.w));
  else if (q == 2) m = fmaxf(v.x, v.y);
  else             m = -1e30f;
  m = fmaxf(m, __shfl_xor(m, 1));
  m = fmaxf(m, __shfl_xor(m, 2));

  float es;
  if (q < 2)       es = __expf(v.x - m) + __expf(v.y - m) + __expf(v.z - m) + __expf(v.w - m);
  else if (q == 2) es = __expf(v.x - m) + __expf(v.y - m);
  else             es = 0.0f;
  es += __shfl_xor(es, 1);
  es += __shfl_xor(es, 2);
  float lse = m + __logf(es);

  if (g == 0 && q < 3) {
    float2* o = (float2*)(out + (size_t)node * 10);  // 8B-aligned always
    if (q < 2) {
      o[q * 2]     = make_float2(v.x - lse, v.y - lse);
      o[q * 2 + 1] = make_float2(v.z - lse, v.w - lse);
    } else {
      o[4] = make_float2(v.x - lse, v.y - lse);
    }
  }
}

extern "C" void kernel_launch(void* const* d_in, const int* in_sizes, int n_in,
                              void* d_out, int out_size, void* d_ws, size_t ws_size,
                              hipStream_t stream) {
  const float* features = (const float*)d_in[0];
  const int* edge_index = (const int*)d_in[1];
  const float* W1_l = (const float*)d_in[2];
  const float* b1   = (const float*)d_in[3];
  const float* W1_r = (const float*)d_in[4];
  const float* W2_l = (const float*)d_in[5];
  const float* b2   = (const float*)d_in[6];
  const float* W2_r = (const float*)d_in[7];
  float* out = (float*)d_out;

  const int N = in_sizes[0] / FEAT;    // 50000
  const int E = in_sizes[1] / 2;       // 1250000
  const int* src = edge_index;
  const int* dst = edge_index + E;

  char* ws = (char*)d_ws;
  int* deg               = (int*)(ws + 0);
  int* partials          = (int*)(ws + 200000);
  int* row_ptr           = (int*)(ws + 200256);
  int* cursor            = (int*)(ws + 400272);
  int* col               = (int*)(ws + 600272);
  unsigned short* p1     = (unsigned short*)(ws + 5600272);
  float* q1h1            = (float*)(ws + 12000272);
  float* p2              = (float*)(ws + 24800272);
  float* q2              = (float*)(ws + 28000272);

  hipMemsetAsync(deg, 0, (size_t)N * sizeof(int), stream);

  int eb8 = ((E + 255) / 256) * 8;   // bucketed: 8 blocks per 256-edge chunk
  int nb1024 = (N + 1023) / 1024;    // 49
  int nb256 = (N + 255) / 256;       // 196
  int nbw = (N + 3) / 4;             // 12500

  hist_kernel<<<eb8, 256, 0, stream>>>(dst, deg, E);
  partial_sum_kernel<<<nb1024, 1024, 0, stream>>>(deg, partials, N);
  scan_partials_kernel<<<1, 64, 0, stream>>>(partials, nb1024);
  scan_tile_kernel<<<nb1024, 1024, 0, stream>>>(deg, partials, row_ptr, cursor, N, E);
  fill_kernel<<<eb8, 256, 0, stream>>>(src, dst, cursor, col, E);

  dense1_kernel<<<dim3(nb256, 8), 256, 0, stream>>>(features, W1_l, W1_r, b1, p1, q1h1, N);
  gather1_kernel<<<nbw, 256, 0, stream>>>(row_ptr, col, (const uint4*)p1, q1h1, N);
  dense2_kernel<<<nb256, 256, 0, stream>>>(q1h1, W2_l, W2_r, b2, p2, q2, N);
  gather2_kernel<<<nbw, 256, 0, stream>>>(row_ptr, col, p2, q2, out, N);
}